// Round 1
// baseline (568.653 us; speedup 1.0000x reference)
//
#include <hip/hip_runtime.h>
#include <math.h>

#define NEGV (-1e9f)

// ---------------------------------------------------------------------------
// K1: build f = [r1_bcast | r2_bcast | edge] on the fly and compute
//     qkv1[mat][row][col] = f_row @ d1_wqkv[mat] + d1_bqkv[mat]
// t -> col = t%48, row = (t/48)%BN, mat = t/(48*BN). Coalesced writes.
// ---------------------------------------------------------------------------
__global__ void qkv1_kernel(const float* __restrict__ r1, const float* __restrict__ r2,
                            const float* __restrict__ edge,
                            const float* __restrict__ wqkv, const float* __restrict__ bqkv,
                            float* __restrict__ qkv1,
                            int B, int M, int F) {
    const int N = M * M;
    const int BN = B * N;
    const int total = 3 * BN * 48;
    int t = blockIdx.x * blockDim.x + threadIdx.x;
    if (t >= total) return;
    int col = t % 48;
    int row = (t / 48) % BN;
    int mat = t / (48 * BN);
    int b = row / N, n = row % N;
    int i = n / M, j = n % M;

    const float* f1 = r1 + (b * M + i) * F;
    const float* f2 = r2 + (b * M + j) * F;
    const float* fe = edge + (size_t)row * F;
    const float* w  = wqkv + mat * 48 * 48 + col;

    float s = bqkv[mat * 48 + col];
#pragma unroll
    for (int d = 0; d < 16; ++d) s = fmaf(f1[d], w[d * 48], s);
#pragma unroll
    for (int d = 0; d < 16; ++d) s = fmaf(f2[d], w[(16 + d) * 48], s);
#pragma unroll
    for (int d = 0; d < 16; ++d) s = fmaf(fe[d], w[(32 + d) * 48], s);
    qkv1[t] = s;
}

// ---------------------------------------------------------------------------
// Generic flash-attention: one query per thread, online softmax,
// K/V/mask streamed through LDS in tiles of 128 keys (broadcast reads).
// Layout: q/k/v/out rows are [H*DH] with head h at cols h*DH.
// Key mask is shared by all queries/heads (mask[b*N + key]).
// ---------------------------------------------------------------------------
template <int DH>
__global__ __launch_bounds__(256) void attn_kernel(
    const float* __restrict__ qg, const float* __restrict__ kg, const float* __restrict__ vg,
    const int* __restrict__ mask, float* __restrict__ outg,
    int B, int H, int N, float scale) {
    const int LD = H * DH;
    int bh = blockIdx.x;
    int b = bh / H, h = bh % H;
    int qi = blockIdx.y * blockDim.x + threadIdx.x;

    float qv[DH];
    {
        const float* qrow = qg + ((size_t)(b * N + qi)) * LD + h * DH;
#pragma unroll
        for (int d = 0; d < DH; ++d) qv[d] = qrow[d];
    }

    __shared__ float kt[128][DH];
    __shared__ float vt[128][DH];
    __shared__ int   mt[128];

    float m = -INFINITY, l = 0.f;
    float acc[DH];
#pragma unroll
    for (int d = 0; d < DH; ++d) acc[d] = 0.f;

    for (int k0 = 0; k0 < N; k0 += 128) {
        __syncthreads();
        for (int idx = threadIdx.x; idx < 128 * DH; idx += 256) {
            int key = idx / DH, d = idx % DH;
            size_t g = ((size_t)(b * N + k0 + key)) * LD + h * DH + d;
            kt[key][d] = kg[g];
            vt[key][d] = vg[g];
        }
        for (int idx = threadIdx.x; idx < 128; idx += 256)
            mt[idx] = mask[b * N + k0 + idx];
        __syncthreads();

        for (int key = 0; key < 128; ++key) {
            float s = 0.f;
#pragma unroll
            for (int d = 0; d < DH; ++d) s = fmaf(qv[d], kt[key][d], s);
            s *= scale;
            if (mt[key] == 0) s = NEGV;
            if (s > m) {
                float corr = __expf(m - s);   // exp(-inf)=0 on first key
                l *= corr;
#pragma unroll
                for (int d = 0; d < DH; ++d) acc[d] *= corr;
                m = s;
            }
            float p = __expf(s - m);
            l += p;
#pragma unroll
            for (int d = 0; d < DH; ++d) acc[d] = fmaf(p, vt[key][d], acc[d]);
        }
    }
    float inv = 1.f / l;
    float* orow = outg + ((size_t)(b * N + qi)) * LD + h * DH;
#pragma unroll
    for (int d = 0; d < DH; ++d) orow[d] = acc[d] * inv;
}

// ---------------------------------------------------------------------------
// out[row][col] = in[row][:KD] @ w[:,col] + b[col]; thread per output.
// ---------------------------------------------------------------------------
template <int KD>
__global__ void proj_kernel(const float* __restrict__ in, const float* __restrict__ w,
                            const float* __restrict__ bias, float* __restrict__ out,
                            int rows, int cols) {
    int t = blockIdx.x * blockDim.x + threadIdx.x;
    if (t >= rows * cols) return;
    int col = t % cols, row = t / cols;
    const float* ir = in + (size_t)row * KD;
    const float* wc = w + col;
    float s = bias[col];
#pragma unroll
    for (int d = 0; d < KD; ++d) s = fmaf(ir[d], wc[d * cols], s);
    out[t] = s;
}

// ---------------------------------------------------------------------------
// qkv[mat][row][c] = in[row][:16] @ wqkv[mat][:,c] + bqkv[mat][c]  (16x16 mats)
// t -> c = t%16, row = (t/16)%rows, mat = t/(16*rows). Coalesced writes.
// ---------------------------------------------------------------------------
__global__ void qkv16_kernel(const float* __restrict__ in, const float* __restrict__ wqkv,
                             const float* __restrict__ bqkv, float* __restrict__ qkv,
                             int rows) {
    int t = blockIdx.x * blockDim.x + threadIdx.x;
    if (t >= 3 * rows * 16) return;
    int c = t % 16;
    int row = (t / 16) % rows;
    int mat = t / (16 * rows);
    const float* ir = in + (size_t)row * 16;
    const float* wc = wqkv + mat * 256 + c;
    float s = bqkv[mat * 16 + c];
#pragma unroll
    for (int d = 0; d < 16; ++d) s = fmaf(ir[d], wc[d * 16], s);
    qkv[t] = s;
}

// ---------------------------------------------------------------------------
// act_raw[row] = attnp[row] @ pol_wo + pol_bo ; crit_raw similarly.
// ---------------------------------------------------------------------------
__global__ void heads_out_kernel(const float* __restrict__ attnp, const float* __restrict__ attnv,
                                 const float* __restrict__ pol_wo, const float* __restrict__ pol_bo,
                                 const float* __restrict__ val_wo, const float* __restrict__ val_bo,
                                 float* __restrict__ act_raw, float* __restrict__ crit_raw,
                                 int rows) {
    int t = blockIdx.x * blockDim.x + threadIdx.x;
    if (t >= rows) return;
    const float* ap = attnp + (size_t)t * 16;
    const float* av = attnv + (size_t)t * 16;
    float sa = pol_bo[0], sc = val_bo[0];
#pragma unroll
    for (int d = 0; d < 16; ++d) sa = fmaf(ap[d], pol_wo[d], sa);
#pragma unroll
    for (int d = 0; d < 16; ++d) sc = fmaf(av[d], val_wo[d], sc);
    act_raw[t] = sa;
    crit_raw[t] = sc;
}

// ---------------------------------------------------------------------------
// Masked softmax over N=1024 per batch. Block per b, 256 threads, 4 vals each.
// ---------------------------------------------------------------------------
__global__ __launch_bounds__(256) void action_softmax_kernel(
    const float* __restrict__ act_raw, const int* __restrict__ mask,
    float* __restrict__ out, int N) {
    int b = blockIdx.x;
    int tid = threadIdx.x;
    int lane = tid & 63, wid = tid >> 6;
    __shared__ float wred[4], sbcast;

    float local[4];
    float mx = -INFINITY;
#pragma unroll
    for (int i = 0; i < 4; ++i) {
        int n = tid + i * 256;
        float a = act_raw[b * N + n];
        if (mask[b * N + n] == 0) a = NEGV;
        local[i] = a;
        mx = fmaxf(mx, a);
    }
#pragma unroll
    for (int o = 32; o > 0; o >>= 1) mx = fmaxf(mx, __shfl_down(mx, o));
    if (lane == 0) wred[wid] = mx;
    __syncthreads();
    if (tid == 0) sbcast = fmaxf(fmaxf(wred[0], wred[1]), fmaxf(wred[2], wred[3]));
    __syncthreads();
    mx = sbcast;

    float s = 0.f;
#pragma unroll
    for (int i = 0; i < 4; ++i) {
        float p = __expf(local[i] - mx);
        local[i] = p;
        s += p;
    }
#pragma unroll
    for (int o = 32; o > 0; o >>= 1) s += __shfl_down(s, o);
    if (lane == 0) wred[wid] = s;
    __syncthreads();
    if (tid == 0) sbcast = wred[0] + wred[1] + wred[2] + wred[3];
    __syncthreads();
    float inv = 1.f / sbcast;
#pragma unroll
    for (int i = 0; i < 4; ++i) out[b * N + tid + i * 256] = local[i] * inv;
}

// ---------------------------------------------------------------------------
// critic[b][c] = crit_raw[b][:N] @ v2_w[:,c] + v2_b[c]. Block per b.
// threads: c = t%16, seg = t/16 (16 segs x 64 keys), LDS reduce.
// ---------------------------------------------------------------------------
__global__ __launch_bounds__(256) void critic_kernel(
    const float* __restrict__ crit_raw, const float* __restrict__ v2w,
    const float* __restrict__ v2b, float* __restrict__ out, int N) {
    int b = blockIdx.x;
    int t = threadIdx.x;
    int c = t & 15, seg = t >> 4;
    __shared__ float red[16][17];
    float s = 0.f;
    int n0 = seg * 64;
    for (int n = n0; n < n0 + 64; ++n)
        s = fmaf(crit_raw[b * N + n], v2w[n * 16 + c], s);
    red[seg][c] = s;
    __syncthreads();
    if (t < 16) {
        float acc = v2b[t];
#pragma unroll
        for (int g = 0; g < 16; ++g) acc += red[g][t];
        out[b * 16 + t] = acc;
    }
}

// ---------------------------------------------------------------------------
extern "C" void kernel_launch(void* const* d_in, const int* in_sizes, int n_in,
                              void* d_out, int out_size, void* d_ws, size_t ws_size,
                              hipStream_t stream) {
    const int B = 16, M = 32, F = 16, H = 4;
    const int N = M * M;          // 1024
    const int BN = B * N;         // 16384

    const float* r1       = (const float*)d_in[0];
    const float* r2       = (const float*)d_in[1];
    const float* edge     = (const float*)d_in[2];
    const int*   mask     = (const int*)d_in[3];
    const float* d1_wqkv  = (const float*)d_in[4];
    const float* d1_bqkv  = (const float*)d_in[5];
    const float* d1_wo    = (const float*)d_in[6];
    const float* d1_bo    = (const float*)d_in[7];
    const float* d2_wqkv  = (const float*)d_in[8];
    const float* d2_bqkv  = (const float*)d_in[9];
    const float* d2_wo    = (const float*)d_in[10];
    const float* d2_bo    = (const float*)d_in[11];
    const float* pol_wqkv = (const float*)d_in[12];
    const float* pol_bqkv = (const float*)d_in[13];
    const float* pol_wo   = (const float*)d_in[14];
    const float* pol_bo   = (const float*)d_in[15];
    const float* val_wqkv = (const float*)d_in[16];
    const float* val_bqkv = (const float*)d_in[17];
    const float* val_wo   = (const float*)d_in[18];
    const float* val_bo   = (const float*)d_in[19];
    const float* v2_w     = (const float*)d_in[20];
    const float* v2_b     = (const float*)d_in[21];

    float* ws = (float*)d_ws;
    float* qkv1   = ws;                       // 3*BN*48
    float* attn1  = qkv1  + 3 * BN * 48;      // BN*48
    float* e1     = attn1 + BN * 48;          // BN*16
    float* qkv2   = e1    + BN * 16;          // 3*BN*16
    float* attn2  = qkv2  + 3 * BN * 16;      // BN*16
    float* e2     = attn2 + BN * 16;          // BN*16
    float* qkvp   = e2    + BN * 16;          // 3*BN*16
    float* qkvv   = qkvp  + 3 * BN * 16;      // 3*BN*16
    float* attnp  = qkvv  + 3 * BN * 16;      // BN*16
    float* attnv  = attnp + BN * 16;          // BN*16
    float* araw   = attnv + BN * 16;          // BN
    float* craw   = araw  + BN;               // BN

    float* out_action = (float*)d_out;        // B*N
    float* out_critic = out_action + BN;      // B*16

    const float scale1 = 1.0f / sqrtf(12.0f);
    const float scale2 = 0.5f;                // 1/sqrt(4)

    // d1: feature build + QKV
    {
        int total = 3 * BN * 48;
        qkv1_kernel<<<(total + 255) / 256, 256, 0, stream>>>(
            r1, r2, edge, d1_wqkv, d1_bqkv, qkv1, B, M, F);
    }
    // d1 attention
    attn_kernel<12><<<dim3(B * H, N / 256), 256, 0, stream>>>(
        qkv1, qkv1 + BN * 48, qkv1 + 2 * BN * 48, mask, attn1, B, H, N, scale1);
    // e1 = attn1 @ d1_wo + d1_bo
    proj_kernel<48><<<(BN * 16 + 255) / 256, 256, 0, stream>>>(
        attn1, d1_wo, d1_bo, e1, BN, 16);
    // qkv2 = e1 @ d2_wqkv + d2_bqkv
    qkv16_kernel<<<(3 * BN * 16 + 255) / 256, 256, 0, stream>>>(
        e1, d2_wqkv, d2_bqkv, qkv2, BN);
    // d2 attention
    attn_kernel<4><<<dim3(B * H, N / 256), 256, 0, stream>>>(
        qkv2, qkv2 + BN * 16, qkv2 + 2 * BN * 16, mask, attn2, B, H, N, scale2);
    // e2 = attn2 @ d2_wo + d2_bo
    proj_kernel<16><<<(BN * 16 + 255) / 256, 256, 0, stream>>>(
        attn2, d2_wo, d2_bo, e2, BN, 16);
    // pol / val QKV
    qkv16_kernel<<<(3 * BN * 16 + 255) / 256, 256, 0, stream>>>(
        e2, pol_wqkv, pol_bqkv, qkvp, BN);
    qkv16_kernel<<<(3 * BN * 16 + 255) / 256, 256, 0, stream>>>(
        e2, val_wqkv, val_bqkv, qkvv, BN);
    // pol / val attention
    attn_kernel<4><<<dim3(B * H, N / 256), 256, 0, stream>>>(
        qkvp, qkvp + BN * 16, qkvp + 2 * BN * 16, mask, attnp, B, H, N, scale2);
    attn_kernel<4><<<dim3(B * H, N / 256), 256, 0, stream>>>(
        qkvv, qkvv + BN * 16, qkvv + 2 * BN * 16, mask, attnv, B, H, N, scale2);
    // head outputs (wo is 16x1)
    heads_out_kernel<<<(BN + 255) / 256, 256, 0, stream>>>(
        attnp, attnv, pol_wo, pol_bo, val_wo, val_bo, araw, craw, BN);
    // masked action softmax -> output 0
    action_softmax_kernel<<<B, 256, 0, stream>>>(araw, mask, out_action, N);
    // critic @ v2_w + v2_b -> output 1
    critic_kernel<<<B, 256, 0, stream>>>(craw, v2_w, v2_b, out_critic, N);
}

// Round 2
// 213.285 us; speedup vs baseline: 2.6662x; 2.6662x over previous
//
#include <hip/hip_runtime.h>
#include <math.h>

#define NEGV (-1e9f)

// ---------------------------------------------------------------------------
// K1: build f = [r1_bcast | r2_bcast | edge] on the fly and compute
//     qkv1[mat][row][col] = f_row @ d1_wqkv[mat] + d1_bqkv[mat]
// ---------------------------------------------------------------------------
__global__ void qkv1_kernel(const float* __restrict__ r1, const float* __restrict__ r2,
                            const float* __restrict__ edge,
                            const float* __restrict__ wqkv, const float* __restrict__ bqkv,
                            float* __restrict__ qkv1,
                            int B, int M, int F) {
    const int N = M * M;
    const int BN = B * N;
    const int total = 3 * BN * 48;
    int t = blockIdx.x * blockDim.x + threadIdx.x;
    if (t >= total) return;
    int col = t % 48;
    int row = (t / 48) % BN;
    int mat = t / (48 * BN);
    int b = row / N, n = row % N;
    int i = n / M, j = n % M;

    const float* f1 = r1 + (b * M + i) * F;
    const float* f2 = r2 + (b * M + j) * F;
    const float* fe = edge + (size_t)row * F;
    const float* w  = wqkv + mat * 48 * 48 + col;

    float s = bqkv[mat * 48 + col];
#pragma unroll
    for (int d = 0; d < 16; ++d) s = fmaf(f1[d], w[d * 48], s);
#pragma unroll
    for (int d = 0; d < 16; ++d) s = fmaf(f2[d], w[(16 + d) * 48], s);
#pragma unroll
    for (int d = 0; d < 16; ++d) s = fmaf(fe[d], w[(32 + d) * 48], s);
    qkv1[t] = s;
}

// ---------------------------------------------------------------------------
// Partial attention, no-max softmax (scores are O(10), fp32 exp is safe;
// masked keys get bias -1e9 -> exp==0). Key-split KSPLIT ways over blockIdx.z
// producing partial (acc, l); combine is a plain sum afterwards.
// Supports two independent problem sets (pol/val fused) via blockIdx.x.
// One query per thread; K/V/maskbias staged in LDS tiles of 128 keys
// (inner reads are wave-broadcast). SPLIT-way independent accumulator chains.
// ---------------------------------------------------------------------------
template <int DH, int KSPLIT>
__global__ __launch_bounds__(256, 4) void attn_partial_kernel(
    const float* __restrict__ q1, const float* __restrict__ k1, const float* __restrict__ v1,
    const float* __restrict__ q2, const float* __restrict__ k2, const float* __restrict__ v2,
    const int* __restrict__ mask,
    float* __restrict__ pacc1, float* __restrict__ pl1,
    float* __restrict__ pacc2, float* __restrict__ pl2,
    int B, int H, int N, float scale) {
    constexpr int SPLIT = (DH <= 4) ? 4 : 2;
    constexpr int NF4R = DH / 4;          // float4s per row
    const int LD = H * DH;
    const int BH = B * H;

    int bhs = blockIdx.x;
    const float* qg; const float* kg; const float* vg;
    float* pacc; float* pl;
    if (bhs < BH) { qg = q1; kg = k1; vg = v1; pacc = pacc1; pl = pl1; }
    else          { qg = q2; kg = k2; vg = v2; pacc = pacc2; pl = pl2; bhs -= BH; }
    int b = bhs / H, h = bhs % H;
    int qi = blockIdx.y * 256 + threadIdx.x;
    const int KCH = N / KSPLIT;
    int kbase = blockIdx.z * KCH;

    float qv[DH];
    {
        const float* qrow = qg + ((size_t)(b * N + qi)) * LD + h * DH;
#pragma unroll
        for (int d = 0; d < DH; ++d) qv[d] = qrow[d] * scale;
    }

    __shared__ __align__(16) float kt[128 * DH];
    __shared__ __align__(16) float vt[128 * DH];
    __shared__ float mb[128];

    float l[SPLIT];
    float acc[SPLIT][DH];
#pragma unroll
    for (int u = 0; u < SPLIT; ++u) {
        l[u] = 0.f;
#pragma unroll
        for (int d = 0; d < DH; ++d) acc[u][d] = 0.f;
    }

    const float4* kg4 = (const float4*)kg;
    const float4* vg4 = (const float4*)vg;

    for (int t0 = 0; t0 < KCH; t0 += 128) {
        __syncthreads();
        constexpr int NF4 = 128 * NF4R;
        for (int i = threadIdx.x; i < NF4; i += 256) {
            int key = i / NF4R;
            int f   = i % NF4R;
            size_t g4 = (((size_t)(b * N + kbase + t0 + key)) * LD + h * DH) / 4 + f;
            ((float4*)kt)[i] = kg4[g4];
            ((float4*)vt)[i] = vg4[g4];
        }
        for (int i = threadIdx.x; i < 128; i += 256)
            mb[i] = mask[b * N + kbase + t0 + i] ? 0.f : NEGV;
        __syncthreads();

#pragma unroll 2
        for (int key0 = 0; key0 < 128; key0 += SPLIT) {
#pragma unroll
            for (int u = 0; u < SPLIT; ++u) {
                int key = key0 + u;
                float s = mb[key];
#pragma unroll
                for (int f = 0; f < NF4R; ++f) {
                    float4 kk = ((const float4*)kt)[key * NF4R + f];
                    s = fmaf(qv[4 * f + 0], kk.x, s);
                    s = fmaf(qv[4 * f + 1], kk.y, s);
                    s = fmaf(qv[4 * f + 2], kk.z, s);
                    s = fmaf(qv[4 * f + 3], kk.w, s);
                }
                float p = __expf(s);
                l[u] += p;
#pragma unroll
                for (int f = 0; f < NF4R; ++f) {
                    float4 vv = ((const float4*)vt)[key * NF4R + f];
                    acc[u][4 * f + 0] = fmaf(p, vv.x, acc[u][4 * f + 0]);
                    acc[u][4 * f + 1] = fmaf(p, vv.y, acc[u][4 * f + 1]);
                    acc[u][4 * f + 2] = fmaf(p, vv.z, acc[u][4 * f + 2]);
                    acc[u][4 * f + 3] = fmaf(p, vv.w, acc[u][4 * f + 3]);
                }
            }
        }
    }

    float lt = 0.f;
#pragma unroll
    for (int u = 0; u < SPLIT; ++u) lt += l[u];
    float at[DH];
#pragma unroll
    for (int d = 0; d < DH; ++d) {
        float a = acc[0][d];
#pragma unroll
        for (int u = 1; u < SPLIT; ++u) a += acc[u][d];
        at[d] = a;
    }
    float* pa = pacc + ((size_t)blockIdx.z * BH / H * N * LD) /*z*BN*LD*/
                + ((size_t)(b * N + qi)) * LD + h * DH;
#pragma unroll
    for (int d = 0; d < DH; ++d) pa[d] = at[d];
    pl[((size_t)blockIdx.z * (size_t)B * N + b * N + qi) * H + h] = lt;
}

// ---------------------------------------------------------------------------
// Sum partials over z and normalize: out[row][col] = sum_z acc / sum_z l
// ---------------------------------------------------------------------------
template <int DH>
__global__ void attn_combine_kernel(const float* __restrict__ pacc, const float* __restrict__ pl,
                                    float* __restrict__ out, int BN, int H, int ksplit) {
    const int LD = H * DH;
    int t = blockIdx.x * blockDim.x + threadIdx.x;
    if (t >= BN * LD) return;
    int row = t / LD, col = t % LD;
    int h = col / DH;
    float a = 0.f, lsum = 0.f;
    for (int z = 0; z < ksplit; ++z) {
        a    += pacc[((size_t)z * BN + row) * LD + col];
        lsum += pl[((size_t)z * BN + row) * H + h];
    }
    out[t] = a / lsum;
}

// ---------------------------------------------------------------------------
// out[row][col] = in[row][:KD] @ w[:,col] + b[col]; thread per output.
// ---------------------------------------------------------------------------
template <int KD>
__global__ void proj_kernel(const float* __restrict__ in, const float* __restrict__ w,
                            const float* __restrict__ bias, float* __restrict__ out,
                            int rows, int cols) {
    int t = blockIdx.x * blockDim.x + threadIdx.x;
    if (t >= rows * cols) return;
    int col = t % cols, row = t / cols;
    const float* ir = in + (size_t)row * KD;
    const float* wc = w + col;
    float s = bias[col];
#pragma unroll
    for (int d = 0; d < KD; ++d) s = fmaf(ir[d], wc[d * cols], s);
    out[t] = s;
}

// ---------------------------------------------------------------------------
// qkv[mat][row][c] = in[row][:16] @ wqkv[mat][:,c] + bqkv[mat][c]
// ---------------------------------------------------------------------------
__global__ void qkv16_kernel(const float* __restrict__ in, const float* __restrict__ wqkv,
                             const float* __restrict__ bqkv, float* __restrict__ qkv,
                             int rows) {
    int t = blockIdx.x * blockDim.x + threadIdx.x;
    if (t >= 3 * rows * 16) return;
    int c = t % 16;
    int row = (t / 16) % rows;
    int mat = t / (16 * rows);
    const float* ir = in + (size_t)row * 16;
    const float* wc = wqkv + mat * 256 + c;
    float s = bqkv[mat * 16 + c];
#pragma unroll
    for (int d = 0; d < 16; ++d) s = fmaf(ir[d], wc[d * 16], s);
    qkv[t] = s;
}

// ---------------------------------------------------------------------------
__global__ void heads_out_kernel(const float* __restrict__ attnp, const float* __restrict__ attnv,
                                 const float* __restrict__ pol_wo, const float* __restrict__ pol_bo,
                                 const float* __restrict__ val_wo, const float* __restrict__ val_bo,
                                 float* __restrict__ act_raw, float* __restrict__ crit_raw,
                                 int rows) {
    int t = blockIdx.x * blockDim.x + threadIdx.x;
    if (t >= rows) return;
    const float* ap = attnp + (size_t)t * 16;
    const float* av = attnv + (size_t)t * 16;
    float sa = pol_bo[0], sc = val_bo[0];
#pragma unroll
    for (int d = 0; d < 16; ++d) sa = fmaf(ap[d], pol_wo[d], sa);
#pragma unroll
    for (int d = 0; d < 16; ++d) sc = fmaf(av[d], val_wo[d], sc);
    act_raw[t] = sa;
    crit_raw[t] = sc;
}

// ---------------------------------------------------------------------------
__global__ __launch_bounds__(256) void action_softmax_kernel(
    const float* __restrict__ act_raw, const int* __restrict__ mask,
    float* __restrict__ out, int N) {
    int b = blockIdx.x;
    int tid = threadIdx.x;
    int lane = tid & 63, wid = tid >> 6;
    __shared__ float wred[4], sbcast;

    float local[4];
    float mx = -INFINITY;
#pragma unroll
    for (int i = 0; i < 4; ++i) {
        int n = tid + i * 256;
        float a = act_raw[b * N + n];
        if (mask[b * N + n] == 0) a = NEGV;
        local[i] = a;
        mx = fmaxf(mx, a);
    }
#pragma unroll
    for (int o = 32; o > 0; o >>= 1) mx = fmaxf(mx, __shfl_down(mx, o));
    if (lane == 0) wred[wid] = mx;
    __syncthreads();
    if (tid == 0) sbcast = fmaxf(fmaxf(wred[0], wred[1]), fmaxf(wred[2], wred[3]));
    __syncthreads();
    mx = sbcast;

    float s = 0.f;
#pragma unroll
    for (int i = 0; i < 4; ++i) {
        float p = __expf(local[i] - mx);
        local[i] = p;
        s += p;
    }
#pragma unroll
    for (int o = 32; o > 0; o >>= 1) s += __shfl_down(s, o);
    if (lane == 0) wred[wid] = s;
    __syncthreads();
    if (tid == 0) sbcast = wred[0] + wred[1] + wred[2] + wred[3];
    __syncthreads();
    float inv = 1.f / sbcast;
#pragma unroll
    for (int i = 0; i < 4; ++i) out[b * N + tid + i * 256] = local[i] * inv;
}

// ---------------------------------------------------------------------------
__global__ __launch_bounds__(256) void critic_kernel(
    const float* __restrict__ crit_raw, const float* __restrict__ v2w,
    const float* __restrict__ v2b, float* __restrict__ out, int N) {
    int b = blockIdx.x;
    int t = threadIdx.x;
    int c = t & 15, seg = t >> 4;
    __shared__ float red[16][17];
    float s = 0.f;
    int n0 = seg * 64;
    for (int n = n0; n < n0 + 64; ++n)
        s = fmaf(crit_raw[b * N + n], v2w[n * 16 + c], s);
    red[seg][c] = s;
    __syncthreads();
    if (t < 16) {
        float acc = v2b[t];
#pragma unroll
        for (int g = 0; g < 16; ++g) acc += red[g][t];
        out[b * 16 + t] = acc;
    }
}

// ---------------------------------------------------------------------------
extern "C" void kernel_launch(void* const* d_in, const int* in_sizes, int n_in,
                              void* d_out, int out_size, void* d_ws, size_t ws_size,
                              hipStream_t stream) {
    const int B = 16, M = 32, F = 16, H = 4;
    const int N = M * M;          // 1024
    const int BN = B * N;         // 16384
    const int KSPLIT = 4;

    const float* r1       = (const float*)d_in[0];
    const float* r2       = (const float*)d_in[1];
    const float* edge     = (const float*)d_in[2];
    const int*   mask     = (const int*)d_in[3];
    const float* d1_wqkv  = (const float*)d_in[4];
    const float* d1_bqkv  = (const float*)d_in[5];
    const float* d1_wo    = (const float*)d_in[6];
    const float* d1_bo    = (const float*)d_in[7];
    const float* d2_wqkv  = (const float*)d_in[8];
    const float* d2_bqkv  = (const float*)d_in[9];
    const float* d2_wo    = (const float*)d_in[10];
    const float* d2_bo    = (const float*)d_in[11];
    const float* pol_wqkv = (const float*)d_in[12];
    const float* pol_bqkv = (const float*)d_in[13];
    const float* pol_wo   = (const float*)d_in[14];
    const float* pol_bo   = (const float*)d_in[15];
    const float* val_wqkv = (const float*)d_in[16];
    const float* val_bqkv = (const float*)d_in[17];
    const float* val_wo   = (const float*)d_in[18];
    const float* val_bo   = (const float*)d_in[19];
    const float* v2_w     = (const float*)d_in[20];
    const float* v2_b     = (const float*)d_in[21];

    float* ws = (float*)d_ws;
    // base layout (floats), with overlays for dead buffers
    float* qkv1     = ws;                         // 3*BN*48 = 2,359,296
    float* scr_pacc = qkv1 + 3 * BN * 48;         // 3,145,728 (max over layers)
    float* scr_pl   = scr_pacc + KSPLIT * BN * 48;// 524,288 (2 sets of KSPLIT*BN*H)
    float* attn1    = scr_pl + 2 * KSPLIT * BN * H; // 786,432
    float* e1       = attn1 + BN * 48;            // 262,144
    float* qkv2     = e1 + BN * 16;               // 786,432
    float* e2       = qkv2 + 3 * BN * 16;         // 262,144
    // overlays
    float* qkvp  = qkv1;                          // qkv1 dead after d1 attn
    float* qkvv  = qkv1 + 3 * BN * 16;
    float* attn2 = attn1;                         // attn1 dead after proj->e1
    float* attnp = attn1 + BN * 16;
    float* attnv = attn1 + 2 * BN * 16;
    float* araw  = e1;                            // e1 dead after qkv2
    float* craw  = e1 + BN;
    float* paccp = scr_pacc;
    float* paccv = scr_pacc + (size_t)KSPLIT * BN * 16;
    float* plp   = scr_pl;
    float* plv   = scr_pl + KSPLIT * BN * H;

    float* out_action = (float*)d_out;            // B*N
    float* out_critic = out_action + BN;          // B*16

    const float scale1 = 1.0f / sqrtf(12.0f);
    const float scale2 = 0.5f;

    // d1: feature build + QKV
    qkv1_kernel<<<(3 * BN * 48 + 255) / 256, 256, 0, stream>>>(
        r1, r2, edge, d1_wqkv, d1_bqkv, qkv1, B, M, F);
    // d1 attention (partial + combine)
    attn_partial_kernel<12, 4><<<dim3(B * H, N / 256, KSPLIT), 256, 0, stream>>>(
        qkv1, qkv1 + BN * 48, qkv1 + 2 * BN * 48,
        qkv1, qkv1 + BN * 48, qkv1 + 2 * BN * 48,
        mask, scr_pacc, scr_pl, scr_pacc, scr_pl, B, H, N, scale1);
    attn_combine_kernel<12><<<(BN * 48 + 255) / 256, 256, 0, stream>>>(
        scr_pacc, scr_pl, attn1, BN, H, KSPLIT);
    // e1 = attn1 @ d1_wo + d1_bo
    proj_kernel<48><<<(BN * 16 + 255) / 256, 256, 0, stream>>>(
        attn1, d1_wo, d1_bo, e1, BN, 16);
    // qkv2 = e1 @ d2_wqkv + d2_bqkv
    qkv16_kernel<<<(3 * BN * 16 + 255) / 256, 256, 0, stream>>>(
        e1, d2_wqkv, d2_bqkv, qkv2, BN);
    // d2 attention
    attn_partial_kernel<4, 4><<<dim3(B * H, N / 256, KSPLIT), 256, 0, stream>>>(
        qkv2, qkv2 + BN * 16, qkv2 + 2 * BN * 16,
        qkv2, qkv2 + BN * 16, qkv2 + 2 * BN * 16,
        mask, scr_pacc, scr_pl, scr_pacc, scr_pl, B, H, N, scale2);
    attn_combine_kernel<4><<<(BN * 16 + 255) / 256, 256, 0, stream>>>(
        scr_pacc, scr_pl, attn2, BN, H, KSPLIT);
    // e2 = attn2 @ d2_wo + d2_bo
    proj_kernel<16><<<(BN * 16 + 255) / 256, 256, 0, stream>>>(
        attn2, d2_wo, d2_bo, e2, BN, 16);
    // pol / val QKV
    qkv16_kernel<<<(3 * BN * 16 + 255) / 256, 256, 0, stream>>>(
        e2, pol_wqkv, pol_bqkv, qkvp, BN);
    qkv16_kernel<<<(3 * BN * 16 + 255) / 256, 256, 0, stream>>>(
        e2, val_wqkv, val_bqkv, qkvv, BN);
    // pol + val attention fused in one launch (two sets)
    attn_partial_kernel<4, 4><<<dim3(2 * B * H, N / 256, KSPLIT), 256, 0, stream>>>(
        qkvp, qkvp + BN * 16, qkvp + 2 * BN * 16,
        qkvv, qkvv + BN * 16, qkvv + 2 * BN * 16,
        mask, paccp, plp, paccv, plv, B, H, N, scale2);
    attn_combine_kernel<4><<<(BN * 16 + 255) / 256, 256, 0, stream>>>(
        paccp, plp, attnp, BN, H, KSPLIT);
    attn_combine_kernel<4><<<(BN * 16 + 255) / 256, 256, 0, stream>>>(
        paccv, plv, attnv, BN, H, KSPLIT);
    // head outputs
    heads_out_kernel<<<(BN + 255) / 256, 256, 0, stream>>>(
        attnp, attnv, pol_wo, pol_bo, val_wo, val_bo, araw, craw, BN);
    // masked action softmax -> output 0
    action_softmax_kernel<<<B, 256, 0, stream>>>(araw, mask, out_action, N);
    // critic @ v2_w + v2_b -> output 1
    critic_kernel<<<B, 256, 0, stream>>>(craw, v2_w, v2_b, out_critic, N);
}